// Round 1
// baseline (375.615 us; speedup 1.0000x reference)
//
#include <hip/hip_runtime.h>

typedef unsigned short u16;
typedef __bf16 bf16x8 __attribute__((ext_vector_type(8)));
typedef float floatx4 __attribute__((ext_vector_type(4)));
typedef u16 u16x4 __attribute__((ext_vector_type(4)));

#define MEG ((size_t)(1u << 20))

__device__ __forceinline__ u16 f2bf(float f) {
  unsigned int u = __float_as_uint(f);
  u += 0x7fffu + ((u >> 16) & 1u);   // round-to-nearest-even
  return (u16)(u >> 16);
}

// async global->LDS, 16B per lane; LDS dest = wave-uniform base + lane*16
__device__ __forceinline__ void load_lds16(const u16* g, u16* l) {
  __builtin_amdgcn_global_load_lds((const __attribute__((address_space(1))) unsigned int*)g,
                                   (__attribute__((address_space(3))) unsigned int*)l,
                                   16, 0, 0);
}

// ---------------- fp32 -> bf16 conversion of the 7 fp32 inputs ----------------
// layout (elements): [q 4M][k 4M][v 4M][Wq 1M][Wk 1M][Wv 1M][Wo 1M] = 16M
__global__ __launch_bounds__(256) void cvt7(
    const float* __restrict__ s0, const float* __restrict__ s1,
    const float* __restrict__ s2, const float* __restrict__ s3,
    const float* __restrict__ s4, const float* __restrict__ s5,
    const float* __restrict__ s6, u16* __restrict__ dst)
{
  size_t e = ((size_t)blockIdx.x * 256 + threadIdx.x) * 4;
  unsigned m = (unsigned)(e >> 20);
  const float* s; size_t off;
  if (m < 4)       { s = s0; off = e; }
  else if (m < 8)  { s = s1; off = e - 4 * MEG; }
  else if (m < 12) { s = s2; off = e - 8 * MEG; }
  else if (m < 13) { s = s3; off = e - 12 * MEG; }
  else if (m < 14) { s = s4; off = e - 13 * MEG; }
  else if (m < 15) { s = s5; off = e - 14 * MEG; }
  else             { s = s6; off = e - 15 * MEG; }
  float4 f = *reinterpret_cast<const float4*>(s + off);
  u16x4 o;
  o.x = f2bf(f.x); o.y = f2bf(f.y); o.z = f2bf(f.z); o.w = f2bf(f.w);
  *reinterpret_cast<u16x4*>(dst + e) = o;
}

// ---------------- generic C = A * B^T (+bias) bf16 MFMA GEMM ----------------
// A: MxK bf16 row-major, B: NxK bf16 row-major, C: MxN (bf16 or fp32)
// 128x128 tile, BK=32, 256 threads = 4 waves (2x2), each wave 64x64 = 4x4 MFMA tiles
template<bool OUT_BF16, bool ADD_BIAS>
__global__ __launch_bounds__(256) void gemm_bt(
    const u16* __restrict__ Abase, const u16* __restrict__ Bbase,
    const float* __restrict__ bias, void* __restrict__ Cbase,
    int M, int N, int K, long zA, long zB, long zC)
{
  __shared__ __align__(16) u16 As[128 * 32];
  __shared__ __align__(16) u16 Bs[128 * 32];
  const int tid = threadIdx.x;
  const int w = tid >> 6, ln = tid & 63;
  const int lm = ln & 15, lq = ln >> 4;
  const int wm = w >> 1, wn = w & 1;
  const long m0 = (long)blockIdx.y * 128, n0 = (long)blockIdx.x * 128;
  const u16* A = Abase + (size_t)blockIdx.z * (size_t)zA;
  const u16* B = Bbase + (size_t)blockIdx.z * (size_t)zB;

  const floatx4 z4 = {0.f, 0.f, 0.f, 0.f};
  floatx4 acc[4][4];
#pragma unroll
  for (int i = 0; i < 4; ++i)
#pragma unroll
    for (int j = 0; j < 4; ++j) acc[i][j] = z4;

  for (int k0 = 0; k0 < K; k0 += 32) {
#pragma unroll
    for (int rr = 0; rr < 2; ++rr) {
      int c = rr * 256 + tid;
      long row = c >> 2; int cg = c & 3;
      load_lds16(A + (m0 + row) * K + k0 + cg * 8, &As[(rr * 256 + w * 64) * 8]);
      load_lds16(B + (n0 + row) * K + k0 + cg * 8, &Bs[(rr * 256 + w * 64) * 8]);
    }
    __syncthreads();
    bf16x8 af[4], bfr[4];
#pragma unroll
    for (int i = 0; i < 4; ++i)
      af[i] = *reinterpret_cast<const bf16x8*>(&As[(wm * 64 + i * 16 + lm) * 32 + lq * 8]);
#pragma unroll
    for (int j = 0; j < 4; ++j)
      bfr[j] = *reinterpret_cast<const bf16x8*>(&Bs[(wn * 64 + j * 16 + lm) * 32 + lq * 8]);
#pragma unroll
    for (int i = 0; i < 4; ++i)
#pragma unroll
      for (int j = 0; j < 4; ++j)
        acc[i][j] = __builtin_amdgcn_mfma_f32_16x16x32_bf16(af[i], bfr[j], acc[i][j], 0, 0, 0);
    __syncthreads();
  }

#pragma unroll
  for (int i = 0; i < 4; ++i) {
    long row = m0 + wm * 64 + i * 16 + lq * 4;
#pragma unroll
    for (int j = 0; j < 4; ++j) {
      long col = n0 + wn * 64 + j * 16 + lm;
#pragma unroll
      for (int r = 0; r < 4; ++r) {
        float v = acc[i][j][r];
        if (ADD_BIAS) v += bias[col];
        size_t idx = (size_t)(row + r) * (size_t)N + (size_t)col;
        if (OUT_BF16) (((u16*)Cbase) + (size_t)blockIdx.z * (size_t)zC)[idx] = f2bf(v);
        else ((float*)Cbase)[idx] = v;
      }
    }
  }
}

// ---------------- V (b,l,h*64+d) -> Vt (bh, d, l) ----------------
__global__ __launch_bounds__(256) void transpose_v(const u16* __restrict__ Vp, u16* __restrict__ Vt)
{
  int o = blockIdx.x * 256 + threadIdx.x;   // over B*H*64*2048 = 4M
  int l = o & 2047;
  int d = (o >> 11) & 63;
  int bh = o >> 17;
  int b = bh >> 4, h = bh & 15;
  Vt[o] = Vp[(size_t)((b << 11) + l) * 1024 + (h << 6) + d];
}

// ---------------- flash attention ----------------
// grid (32 q-tiles, 32 bh), 256 threads = 4 waves, each wave: 16 q-rows x hd=64
__global__ __launch_bounds__(256) void attn_kernel(
    const u16* __restrict__ Qp, const u16* __restrict__ Kp,
    const u16* __restrict__ Vt, const int* __restrict__ mask,
    u16* __restrict__ ctx)
{
  __shared__ __align__(16) u16 Ks[32 * 64];    // [key][d]
  __shared__ __align__(16) u16 Vts[64 * 32];   // [d][key]
  __shared__ __align__(16) u16 Ps[4 * 16 * 32];// per-wave [q][key]
  __shared__ float mb[32];

  const int tid = threadIdx.x;
  const int w = tid >> 6, ln = tid & 63;
  const int lm = ln & 15, lq = ln >> 4;
  const int bh = blockIdx.y, b = bh >> 4, h = bh & 15;
  const int q0 = blockIdx.x * 64;

  const u16* Qh = Qp + (size_t)b * 2048 * 1024 + h * 64;
  const u16* Kh = Kp + (size_t)b * 2048 * 1024 + h * 64;
  const u16* Vth = Vt + (size_t)bh * 64 * 2048;

  // persistent Q fragments (A-operand layout: m=lane&15, k=(lane>>4)*8+j)
  const int qrow = q0 + w * 16 + lm;
  bf16x8 qf0 = *reinterpret_cast<const bf16x8*>(Qh + (size_t)qrow * 1024 + lq * 8);
  bf16x8 qf1 = *reinterpret_cast<const bf16x8*>(Qh + (size_t)qrow * 1024 + 32 + lq * 8);

  const floatx4 z4 = {0.f, 0.f, 0.f, 0.f};
  floatx4 O[4];
#pragma unroll
  for (int j = 0; j < 4; ++j) O[j] = z4;
  float mrow[4], lrow[4];
#pragma unroll
  for (int r = 0; r < 4; ++r) { mrow[r] = -1e30f; lrow[r] = 0.f; }

  u16* Psw = &Ps[w * 512];

  for (int k0 = 0; k0 < 2048; k0 += 32) {
    // stage K tile [32][64] and Vt tile [64][32] (256 x 16B chunks each)
    load_lds16(Kh + (size_t)(k0 + (tid >> 3)) * 1024 + (tid & 7) * 8, &Ks[w * 512]);
    load_lds16(Vth + (size_t)(tid >> 2) * 2048 + k0 + (tid & 3) * 8, &Vts[w * 512]);
    if (tid < 32) mb[tid] = (mask[b * 2048 + k0 + tid] != 0) ? 0.f : -1e30f;
    __syncthreads();

    // S = Q(16x64) * K_tile^T(64x32): 2 n-tiles x 2 chained k-steps
    bf16x8 kf00 = *reinterpret_cast<const bf16x8*>(&Ks[lm * 64 + lq * 8]);
    bf16x8 kf01 = *reinterpret_cast<const bf16x8*>(&Ks[lm * 64 + 32 + lq * 8]);
    bf16x8 kf10 = *reinterpret_cast<const bf16x8*>(&Ks[(16 + lm) * 64 + lq * 8]);
    bf16x8 kf11 = *reinterpret_cast<const bf16x8*>(&Ks[(16 + lm) * 64 + 32 + lq * 8]);

    floatx4 S0 = __builtin_amdgcn_mfma_f32_16x16x32_bf16(qf0, kf00, z4, 0, 0, 0);
    S0 = __builtin_amdgcn_mfma_f32_16x16x32_bf16(qf1, kf01, S0, 0, 0, 0);
    floatx4 S1 = __builtin_amdgcn_mfma_f32_16x16x32_bf16(qf0, kf10, z4, 0, 0, 0);
    S1 = __builtin_amdgcn_mfma_f32_16x16x32_bf16(qf1, kf11, S1, 0, 0, 0);

    float mb0 = mb[lm], mb1 = mb[16 + lm];

#pragma unroll
    for (int r = 0; r < 4; ++r) {
      float sa = S0[r] * 0.125f + mb0;   // row = lq*4+r, col = lm
      float sb = S1[r] * 0.125f + mb1;   // col = 16+lm
      float tm = fmaxf(sa, sb);
#pragma unroll
      for (int off = 1; off < 16; off <<= 1) tm = fmaxf(tm, __shfl_xor(tm, off, 64));
      float mn = fmaxf(mrow[r], tm);
      float al = __expf(mrow[r] - mn);   // -1e30 - -1e30 = 0 -> 1 (safe)
      float p0 = __expf(sa - mn);
      float p1 = __expf(sb - mn);
      float ts = p0 + p1;
#pragma unroll
      for (int off = 1; off < 16; off <<= 1) ts += __shfl_xor(ts, off, 64);
      lrow[r] = lrow[r] * al + ts;
      mrow[r] = mn;
      O[0][r] *= al; O[1][r] *= al; O[2][r] *= al; O[3][r] *= al;
      Psw[(lq * 4 + r) * 32 + lm] = f2bf(p0);
      Psw[(lq * 4 + r) * 32 + 16 + lm] = f2bf(p1);
    }

    // O += P(16x32) * V(32x64)  (Vt rows give B^T form; per-wave Ps, same-wave
    // DS ordering guarantees write->read correctness without a barrier)
    bf16x8 pf = *reinterpret_cast<const bf16x8*>(&Psw[lm * 32 + lq * 8]);
#pragma unroll
    for (int j = 0; j < 4; ++j) {
      bf16x8 vf = *reinterpret_cast<const bf16x8*>(&Vts[(j * 16 + lm) * 32 + lq * 8]);
      O[j] = __builtin_amdgcn_mfma_f32_16x16x32_bf16(pf, vf, O[j], 0, 0, 0);
    }
    __syncthreads();
  }

#pragma unroll
  for (int r = 0; r < 4; ++r) {
    float inv = 1.0f / lrow[r];
    int row = q0 + w * 16 + lq * 4 + r;
    size_t base = ((size_t)b * 2048 + row) * 1024 + h * 64 + lm;
#pragma unroll
    for (int j = 0; j < 4; ++j)
      ctx[base + j * 16] = f2bf(O[j][r] * inv);
  }
}

// ---------------- host ----------------
extern "C" void kernel_launch(void* const* d_in, const int* in_sizes, int n_in,
                              void* d_out, int out_size, void* d_ws, size_t ws_size,
                              hipStream_t stream) {
  const float* q  = (const float*)d_in[0];
  const float* k  = (const float*)d_in[1];
  const float* v  = (const float*)d_in[2];
  const int*   mk = (const int*)  d_in[3];
  const float* wq = (const float*)d_in[4];
  const float* wk = (const float*)d_in[5];
  const float* wv = (const float*)d_in[6];
  const float* wo = (const float*)d_in[7];
  const float* bo = (const float*)d_in[8];

  u16* ws16 = (u16*)d_ws;
  // element offsets (bf16), 1 MEG = 1M elements:
  // Xq=0 Xk=4M Xv=8M | Wq=12M Wk=13M Wv=14M Wo=15M | Qp=16M Kp=20M Vp=24M
  // Vt aliases Xq (dead after proj GEMM); ctx aliases Xk.
  u16* Xq  = ws16;
  u16* Wq  = ws16 + 12 * MEG;
  u16* Wo  = ws16 + 15 * MEG;
  u16* Qp  = ws16 + 16 * MEG;
  u16* Kp  = ws16 + 20 * MEG;
  u16* Vp  = ws16 + 24 * MEG;
  u16* Vt  = ws16;            // alias Xq
  u16* ctx = ws16 + 4 * MEG;  // alias Xk

  cvt7<<<dim3(16384), dim3(256), 0, stream>>>(q, k, v, wq, wk, wv, wo, ws16);

  gemm_bt<true, false><<<dim3(8, 32, 3), dim3(256), 0, stream>>>(
      Xq, Wq, nullptr, (void*)Qp, 4096, 1024, 1024,
      (long)(4 * MEG), (long)MEG, (long)(4 * MEG));

  transpose_v<<<dim3(16384), dim3(256), 0, stream>>>(Vp, Vt);

  attn_kernel<<<dim3(32, 32), dim3(256), 0, stream>>>(Qp, Kp, Vt, mk, ctx);

  gemm_bt<false, true><<<dim3(8, 32, 1), dim3(256), 0, stream>>>(
      ctx, Wo, bo, d_out, 4096, 1024, 1024, 0, 0, 0);
}

// Round 2
// 261.764 us; speedup vs baseline: 1.4349x; 1.4349x over previous
//
#include <hip/hip_runtime.h>

typedef unsigned short u16;
typedef __bf16 bf16x8 __attribute__((ext_vector_type(8)));
typedef float floatx4 __attribute__((ext_vector_type(4)));
typedef u16 u16x4 __attribute__((ext_vector_type(4)));

#define MEG ((size_t)(1u << 20))

__device__ __forceinline__ u16 f2bf(float f) {
  unsigned int u = __float_as_uint(f);
  u += 0x7fffu + ((u >> 16) & 1u);   // round-to-nearest-even
  return (u16)(u >> 16);
}

// async global->LDS, 16B per lane; LDS dest = wave-uniform base + lane*16
__device__ __forceinline__ void load_lds16(const u16* g, u16* l) {
  __builtin_amdgcn_global_load_lds((const __attribute__((address_space(1))) unsigned int*)g,
                                   (__attribute__((address_space(3))) unsigned int*)l,
                                   16, 0, 0);
}

// ---------------- fp32 -> bf16 conversion of the 7 fp32 inputs ----------------
// layout (elements): [q 4M][k 4M][v 4M][Wq 1M][Wk 1M][Wv 1M][Wo 1M] = 16M
__global__ __launch_bounds__(256) void cvt7(
    const float* __restrict__ s0, const float* __restrict__ s1,
    const float* __restrict__ s2, const float* __restrict__ s3,
    const float* __restrict__ s4, const float* __restrict__ s5,
    const float* __restrict__ s6, u16* __restrict__ dst)
{
  size_t e = ((size_t)blockIdx.x * 256 + threadIdx.x) * 4;
  unsigned m = (unsigned)(e >> 20);
  const float* s; size_t off;
  if (m < 4)       { s = s0; off = e; }
  else if (m < 8)  { s = s1; off = e - 4 * MEG; }
  else if (m < 12) { s = s2; off = e - 8 * MEG; }
  else if (m < 13) { s = s3; off = e - 12 * MEG; }
  else if (m < 14) { s = s4; off = e - 13 * MEG; }
  else if (m < 15) { s = s5; off = e - 14 * MEG; }
  else             { s = s6; off = e - 15 * MEG; }
  float4 f = *reinterpret_cast<const float4*>(s + off);
  u16x4 o;
  o.x = f2bf(f.x); o.y = f2bf(f.y); o.z = f2bf(f.z); o.w = f2bf(f.w);
  *reinterpret_cast<u16x4*>(dst + e) = o;
}

// ---------------- generic C = A * B^T (+bias) bf16 MFMA GEMM ----------------
// A: MxK bf16 row-major, B: NxK bf16 row-major, C: MxN (bf16 or fp32)
// 128x128 tile, BK=32, 256 threads = 4 waves (2x2), each wave 64x64 = 4x4 MFMA tiles
template<bool OUT_BF16, bool ADD_BIAS>
__global__ __launch_bounds__(256) void gemm_bt(
    const u16* __restrict__ Abase, const u16* __restrict__ Bbase,
    const float* __restrict__ bias, void* __restrict__ Cbase,
    int M, int N, int K, long zA, long zB, long zC)
{
  __shared__ __align__(16) u16 As[128 * 32];
  __shared__ __align__(16) u16 Bs[128 * 32];
  const int tid = threadIdx.x;
  const int w = tid >> 6, ln = tid & 63;
  const int lm = ln & 15, lq = ln >> 4;
  const int wm = w >> 1, wn = w & 1;
  const long m0 = (long)blockIdx.y * 128, n0 = (long)blockIdx.x * 128;
  const u16* A = Abase + (size_t)blockIdx.z * (size_t)zA;
  const u16* B = Bbase + (size_t)blockIdx.z * (size_t)zB;

  const floatx4 z4 = {0.f, 0.f, 0.f, 0.f};
  floatx4 acc[4][4];
#pragma unroll
  for (int i = 0; i < 4; ++i)
#pragma unroll
    for (int j = 0; j < 4; ++j) acc[i][j] = z4;

  for (int k0 = 0; k0 < K; k0 += 32) {
#pragma unroll
    for (int rr = 0; rr < 2; ++rr) {
      int c = rr * 256 + tid;
      long row = c >> 2; int cg = c & 3;
      load_lds16(A + (m0 + row) * K + k0 + cg * 8, &As[(rr * 256 + w * 64) * 8]);
      load_lds16(B + (n0 + row) * K + k0 + cg * 8, &Bs[(rr * 256 + w * 64) * 8]);
    }
    __syncthreads();
    bf16x8 af[4], bfr[4];
#pragma unroll
    for (int i = 0; i < 4; ++i)
      af[i] = *reinterpret_cast<const bf16x8*>(&As[(wm * 64 + i * 16 + lm) * 32 + lq * 8]);
#pragma unroll
    for (int j = 0; j < 4; ++j)
      bfr[j] = *reinterpret_cast<const bf16x8*>(&Bs[(wn * 64 + j * 16 + lm) * 32 + lq * 8]);
#pragma unroll
    for (int i = 0; i < 4; ++i)
#pragma unroll
      for (int j = 0; j < 4; ++j)
        acc[i][j] = __builtin_amdgcn_mfma_f32_16x16x32_bf16(af[i], bfr[j], acc[i][j], 0, 0, 0);
    __syncthreads();
  }

#pragma unroll
  for (int i = 0; i < 4; ++i) {
    long row = m0 + wm * 64 + i * 16 + lq * 4;
#pragma unroll
    for (int j = 0; j < 4; ++j) {
      long col = n0 + wn * 64 + j * 16 + lm;
#pragma unroll
      for (int r = 0; r < 4; ++r) {
        float v = acc[i][j][r];
        if (ADD_BIAS) v += bias[col];
        size_t idx = (size_t)(row + r) * (size_t)N + (size_t)col;
        if (OUT_BF16) (((u16*)Cbase) + (size_t)blockIdx.z * (size_t)zC)[idx] = f2bf(v);
        else ((float*)Cbase)[idx] = v;
      }
    }
  }
}

// ---------------- V (b,l,h*64+d) -> Vt (bh, d, l), LDS-tiled ----------------
// grid (32 l-tiles, 32 bh); 64x64 u16 tile, coalesced 16B loads and stores
__global__ __launch_bounds__(256) void transpose_v(const u16* __restrict__ Vp, u16* __restrict__ Vt)
{
  __shared__ u16 T[64 * 80];   // pitch 80 el keeps 16B alignment
  const int tid = threadIdx.x;
  const int bh = blockIdx.y, b = bh >> 4, h = bh & 15;
  const int l0 = blockIdx.x * 64;
#pragma unroll
  for (int t = 0; t < 2; ++t) {
    int ci = t * 256 + tid;
    int l = ci >> 3, c = ci & 7;
    *reinterpret_cast<uint4*>(&T[l * 80 + c * 8]) =
      *reinterpret_cast<const uint4*>(&Vp[((size_t)(b * 2048 + l0 + l)) * 1024 + h * 64 + c * 8]);
  }
  __syncthreads();
#pragma unroll
  for (int t = 0; t < 2; ++t) {
    int ci = t * 256 + tid;
    int d = ci >> 3, lg = ci & 7;
    u16 tmp[8];
#pragma unroll
    for (int s = 0; s < 8; ++s) tmp[s] = T[(lg * 8 + s) * 80 + d];
    *reinterpret_cast<uint4*>(&Vt[(size_t)bh * 131072 + (size_t)d * 2048 + l0 + lg * 8]) =
      *reinterpret_cast<uint4*>(tmp);
  }
}

// ---------------- flash attention (max-free softmax, swizzled LDS) ----------------
// grid (16 q-tiles of 128, 32 bh), 4 waves; each wave: 32 q-rows (2 m-tiles), K-tile 64.
// LDS layouts store 8-elem chunks at swizzled slots for uniform bank histograms:
//   Ks/Vts: slot = kc ^ (row&7) (XOR, involution needed by staging)
//   Ps:     slot = (kc + (row>>1)) & 7 (rotation spreads the lq axis of scalar writes)
__global__ __launch_bounds__(256, 2) void attn_kernel(
    const u16* __restrict__ Qp, const u16* __restrict__ Kp,
    const u16* __restrict__ Vt, const int* __restrict__ mask,
    u16* __restrict__ ctx)
{
  __shared__ __align__(16) u16 Ks[64 * 64];      // [key][64 d, swizzled chunks]  8 KB
  __shared__ __align__(16) u16 Vts[64 * 64];     // [d][64 key, swizzled chunks]  8 KB
  __shared__ __align__(16) u16 Ps[4 * 2 * 16 * 64]; // per wave, per m-tile       16 KB
  __shared__ float mb[64];

  const int tid = threadIdx.x;
  const int w = tid >> 6, ln = tid & 63;
  const int lm = ln & 15, lq = ln >> 4;
  const int bh = blockIdx.y, b = bh >> 4, h = bh & 15;
  const int q0 = blockIdx.x * 128;

  const u16* Qh = Qp + (size_t)b * 2048 * 1024 + h * 64;
  const u16* Kh = Kp + (size_t)b * 2048 * 1024 + h * 64;
  const u16* Vth = Vt + (size_t)bh * 64 * 2048;

  // persistent Q fragments: 2 m-tiles x 2 k-halves
  bf16x8 qf[2][2];
#pragma unroll
  for (int m = 0; m < 2; ++m) {
    int qrow = q0 + w * 32 + m * 16 + lm;
#pragma unroll
    for (int h2 = 0; h2 < 2; ++h2)
      qf[m][h2] = *reinterpret_cast<const bf16x8*>(Qh + (size_t)qrow * 1024 + h2 * 32 + lq * 8);
  }

  const floatx4 z4 = {0.f, 0.f, 0.f, 0.f};
  floatx4 O[2][4];
  float psum[2][4];
#pragma unroll
  for (int m = 0; m < 2; ++m)
#pragma unroll
    for (int j = 0; j < 4; ++j) { O[m][j] = z4; psum[m][j] = 0.f; }

  u16* Psw = &Ps[w * 2048];
  const float SCL = 0.18033688011112042f;  // log2(e) / sqrt(64)

  for (int k0 = 0; k0 < 2048; k0 += 64) {
    // stage K tile [64 keys][64 d] and Vt tile [64 d][64 keys], chunk-swizzled
#pragma unroll
    for (int t = 0; t < 2; ++t) {
      int ci = t * 256 + tid;
      int row = ci >> 3, s = ci & 7;
      int kc = s ^ (row & 7);
      load_lds16(Kh + (size_t)(k0 + row) * 1024 + kc * 8, &Ks[(t * 256 + w * 64) * 8]);
      load_lds16(Vth + (size_t)row * 2048 + k0 + kc * 8, &Vts[(t * 256 + w * 64) * 8]);
    }
    if (tid < 64) mb[tid] = (mask[b * 2048 + k0 + tid] != 0) ? 0.f : -1e30f;
    __syncthreads();

    // fragment loads (shared across both m-tiles)
    bf16x8 kf[4][2], vf[4][2];
    float mcol[4];
#pragma unroll
    for (int n = 0; n < 4; ++n) {
      int key = n * 16 + lm;
      mcol[n] = mb[key];
#pragma unroll
      for (int h2 = 0; h2 < 2; ++h2) {
        int slot = (h2 * 4 + lq) ^ (key & 7);
        kf[n][h2] = *reinterpret_cast<const bf16x8*>(&Ks[key * 64 + slot * 8]);
      }
    }
#pragma unroll
    for (int j = 0; j < 4; ++j) {
      int d = j * 16 + lm;
#pragma unroll
      for (int h2 = 0; h2 < 2; ++h2) {
        int slot = (h2 * 4 + lq) ^ (d & 7);
        vf[j][h2] = *reinterpret_cast<const bf16x8*>(&Vts[d * 64 + slot * 8]);
      }
    }

#pragma unroll
    for (int m = 0; m < 2; ++m) {
      // S = Q(16x64) * K^T(64x64) -> 4 n-tiles
      floatx4 S[4];
#pragma unroll
      for (int n = 0; n < 4; ++n) {
        S[n] = __builtin_amdgcn_mfma_f32_16x16x32_bf16(qf[m][0], kf[n][0], z4, 0, 0, 0);
        S[n] = __builtin_amdgcn_mfma_f32_16x16x32_bf16(qf[m][1], kf[n][1], S[n], 0, 0, 0);
      }
      // max-free softmax: p = exp2(S*log2e/8 + maskbias); per-lane partial row sums
      u16* Pm = Psw + m * 1024;
      int kcb = lm >> 3;
#pragma unroll
      for (int n = 0; n < 4; ++n) {
        int kc = n * 2 + kcb;
#pragma unroll
        for (int r = 0; r < 4; ++r) {
          int row = lq * 4 + r;
          float p = exp2f(S[n][r] * SCL + mcol[n]);
          psum[m][r] += p;
          int slot = (kc + (row >> 1)) & 7;
          Pm[row * 64 + slot * 8 + (lm & 7)] = f2bf(p);
        }
      }
      // O += P(16x64) * V(64x64)  (per-wave Ps: same-wave DS order, no barrier)
#pragma unroll
      for (int h2 = 0; h2 < 2; ++h2) {
        int slot = ((h2 * 4 + lq) + (lm >> 1)) & 7;
        bf16x8 pf = *reinterpret_cast<const bf16x8*>(&Pm[lm * 64 + slot * 8]);
#pragma unroll
        for (int j = 0; j < 4; ++j)
          O[m][j] = __builtin_amdgcn_mfma_f32_16x16x32_bf16(pf, vf[j][h2], O[m][j], 0, 0, 0);
      }
    }
    __syncthreads();
  }

  // epilogue: single cross-lane reduction of the row sums, normalize, store
#pragma unroll
  for (int m = 0; m < 2; ++m) {
#pragma unroll
    for (int r = 0; r < 4; ++r) {
      float s = psum[m][r];
      s += __shfl_xor(s, 1, 64);
      s += __shfl_xor(s, 2, 64);
      s += __shfl_xor(s, 4, 64);
      s += __shfl_xor(s, 8, 64);
      float inv = 1.0f / s;
      int row = q0 + w * 32 + m * 16 + lq * 4 + r;
      size_t base = ((size_t)b * 2048 + row) * 1024 + h * 64 + lm;
#pragma unroll
      for (int j = 0; j < 4; ++j)
        ctx[base + j * 16] = f2bf(O[m][j][r] * inv);
    }
  }
}

// ---------------- host ----------------
extern "C" void kernel_launch(void* const* d_in, const int* in_sizes, int n_in,
                              void* d_out, int out_size, void* d_ws, size_t ws_size,
                              hipStream_t stream) {
  const float* q  = (const float*)d_in[0];
  const float* k  = (const float*)d_in[1];
  const float* v  = (const float*)d_in[2];
  const int*   mk = (const int*)  d_in[3];
  const float* wq = (const float*)d_in[4];
  const float* wk = (const float*)d_in[5];
  const float* wv = (const float*)d_in[6];
  const float* wo = (const float*)d_in[7];
  const float* bo = (const float*)d_in[8];

  u16* ws16 = (u16*)d_ws;
  // element offsets (bf16): Xq=0 Xk=4M Xv=8M | Wq=12M Wk=13M Wv=14M Wo=15M
  // Qp=16M Kp=20M Vp=24M | Vt aliases Xq (dead), ctx aliases Xk.
  u16* Xq  = ws16;
  u16* Wq  = ws16 + 12 * MEG;
  u16* Wo  = ws16 + 15 * MEG;
  u16* Qp  = ws16 + 16 * MEG;
  u16* Kp  = ws16 + 20 * MEG;
  u16* Vp  = ws16 + 24 * MEG;
  u16* Vt  = ws16;            // alias Xq
  u16* ctx = ws16 + 4 * MEG;  // alias Xk

  cvt7<<<dim3(16384), dim3(256), 0, stream>>>(q, k, v, wq, wk, wv, wo, ws16);

  gemm_bt<true, false><<<dim3(8, 32, 3), dim3(256), 0, stream>>>(
      Xq, Wq, nullptr, (void*)Qp, 4096, 1024, 1024,
      (long)(4 * MEG), (long)MEG, (long)(4 * MEG));

  transpose_v<<<dim3(32, 32), dim3(256), 0, stream>>>(Vp, Vt);

  attn_kernel<<<dim3(16, 32), dim3(256), 0, stream>>>(Qp, Kp, Vt, mk, ctx);

  gemm_bt<false, true><<<dim3(8, 32, 1), dim3(256), 0, stream>>>(
      ctx, Wo, bo, d_out, 4096, 1024, 1024, 0, 0, 0);
}

// Round 3
// 260.988 us; speedup vs baseline: 1.4392x; 1.0030x over previous
//
#include <hip/hip_runtime.h>

typedef unsigned short u16;
typedef __bf16 bf16x8 __attribute__((ext_vector_type(8)));
typedef __bf16 bf16x4 __attribute__((ext_vector_type(4)));
typedef float floatx4 __attribute__((ext_vector_type(4)));
typedef u16 u16x4 __attribute__((ext_vector_type(4)));

#define MEG ((size_t)(1u << 20))

__device__ __forceinline__ u16 f2bf(float f) {
  unsigned int u = __float_as_uint(f);
  u += 0x7fffu + ((u >> 16) & 1u);   // round-to-nearest-even
  return (u16)(u >> 16);
}
__device__ __forceinline__ unsigned pk2(float a, float b) {
  return (unsigned)f2bf(a) | ((unsigned)f2bf(b) << 16);
}

// async global->LDS, 16B per lane; LDS dest = wave-uniform base + lane*16
__device__ __forceinline__ void load_lds16(const u16* g, u16* l) {
  __builtin_amdgcn_global_load_lds((const __attribute__((address_space(1))) unsigned int*)g,
                                   (__attribute__((address_space(3))) unsigned int*)l,
                                   16, 0, 0);
}

// ---------------- fp32 -> bf16 conversion of the 7 fp32 inputs ----------------
// layout (elements): [q 4M][k 4M][v 4M][Wq 1M][Wk 1M][Wv 1M][Wo 1M] = 16M
__global__ __launch_bounds__(256) void cvt7(
    const float* __restrict__ s0, const float* __restrict__ s1,
    const float* __restrict__ s2, const float* __restrict__ s3,
    const float* __restrict__ s4, const float* __restrict__ s5,
    const float* __restrict__ s6, u16* __restrict__ dst)
{
  size_t e = ((size_t)blockIdx.x * 256 + threadIdx.x) * 4;
  unsigned m = (unsigned)(e >> 20);
  const float* s; size_t off;
  if (m < 4)       { s = s0; off = e; }
  else if (m < 8)  { s = s1; off = e - 4 * MEG; }
  else if (m < 12) { s = s2; off = e - 8 * MEG; }
  else if (m < 13) { s = s3; off = e - 12 * MEG; }
  else if (m < 14) { s = s4; off = e - 13 * MEG; }
  else if (m < 15) { s = s5; off = e - 14 * MEG; }
  else             { s = s6; off = e - 15 * MEG; }
  float4 f = *reinterpret_cast<const float4*>(s + off);
  u16x4 o;
  o.x = f2bf(f.x); o.y = f2bf(f.y); o.z = f2bf(f.z); o.w = f2bf(f.w);
  *reinterpret_cast<u16x4*>(dst + e) = o;
}

// ---------------- generic C = A * B^T (+bias) bf16 MFMA GEMM ----------------
// A: MxK bf16 row-major, B: NxK bf16 row-major, C: MxN (bf16 or fp32)
// 128x128 tile, BK=32, 256 threads = 4 waves (2x2), each wave 64x64 = 4x4 MFMA tiles
template<bool OUT_BF16, bool ADD_BIAS>
__global__ __launch_bounds__(256) void gemm_bt(
    const u16* __restrict__ Abase, const u16* __restrict__ Bbase,
    const float* __restrict__ bias, void* __restrict__ Cbase,
    int M, int N, int K, long zA, long zB, long zC)
{
  __shared__ __align__(16) u16 As[128 * 32];
  __shared__ __align__(16) u16 Bs[128 * 32];
  const int tid = threadIdx.x;
  const int w = tid >> 6, ln = tid & 63;
  const int lm = ln & 15, lq = ln >> 4;
  const int wm = w >> 1, wn = w & 1;
  const long m0 = (long)blockIdx.y * 128, n0 = (long)blockIdx.x * 128;
  const u16* A = Abase + (size_t)blockIdx.z * (size_t)zA;
  const u16* B = Bbase + (size_t)blockIdx.z * (size_t)zB;

  const floatx4 z4 = {0.f, 0.f, 0.f, 0.f};
  floatx4 acc[4][4];
#pragma unroll
  for (int i = 0; i < 4; ++i)
#pragma unroll
    for (int j = 0; j < 4; ++j) acc[i][j] = z4;

  for (int k0 = 0; k0 < K; k0 += 32) {
#pragma unroll
    for (int rr = 0; rr < 2; ++rr) {
      int c = rr * 256 + tid;
      long row = c >> 2; int cg = c & 3;
      load_lds16(A + (m0 + row) * K + k0 + cg * 8, &As[(rr * 256 + w * 64) * 8]);
      load_lds16(B + (n0 + row) * K + k0 + cg * 8, &Bs[(rr * 256 + w * 64) * 8]);
    }
    __syncthreads();
    bf16x8 af[4], bfr[4];
#pragma unroll
    for (int i = 0; i < 4; ++i)
      af[i] = *reinterpret_cast<const bf16x8*>(&As[(wm * 64 + i * 16 + lm) * 32 + lq * 8]);
#pragma unroll
    for (int j = 0; j < 4; ++j)
      bfr[j] = *reinterpret_cast<const bf16x8*>(&Bs[(wn * 64 + j * 16 + lm) * 32 + lq * 8]);
#pragma unroll
    for (int i = 0; i < 4; ++i)
#pragma unroll
      for (int j = 0; j < 4; ++j)
        acc[i][j] = __builtin_amdgcn_mfma_f32_16x16x32_bf16(af[i], bfr[j], acc[i][j], 0, 0, 0);
    __syncthreads();
  }

#pragma unroll
  for (int i = 0; i < 4; ++i) {
    long row = m0 + wm * 64 + i * 16 + lq * 4;
#pragma unroll
    for (int j = 0; j < 4; ++j) {
      long col = n0 + wn * 64 + j * 16 + lm;
#pragma unroll
      for (int r = 0; r < 4; ++r) {
        float v = acc[i][j][r];
        if (ADD_BIAS) v += bias[col];
        size_t idx = (size_t)(row + r) * (size_t)N + (size_t)col;
        if (OUT_BF16) (((u16*)Cbase) + (size_t)blockIdx.z * (size_t)zC)[idx] = f2bf(v);
        else ((float*)Cbase)[idx] = v;
      }
    }
  }
}

// ---------------- V (b,l,h*64+d) -> Vt (bh, d, l), LDS-tiled ----------------
__global__ __launch_bounds__(256) void transpose_v(const u16* __restrict__ Vp, u16* __restrict__ Vt)
{
  __shared__ u16 T[64 * 80];   // pitch 80 el keeps 16B alignment
  const int tid = threadIdx.x;
  const int bh = blockIdx.y, b = bh >> 4, h = bh & 15;
  const int l0 = blockIdx.x * 64;
#pragma unroll
  for (int t = 0; t < 2; ++t) {
    int ci = t * 256 + tid;
    int l = ci >> 3, c = ci & 7;
    *reinterpret_cast<uint4*>(&T[l * 80 + c * 8]) =
      *reinterpret_cast<const uint4*>(&Vp[((size_t)(b * 2048 + l0 + l)) * 1024 + h * 64 + c * 8]);
  }
  __syncthreads();
#pragma unroll
  for (int t = 0; t < 2; ++t) {
    int ci = t * 256 + tid;
    int d = ci >> 3, lg = ci & 7;
    u16 tmp[8];
#pragma unroll
    for (int s = 0; s < 8; ++s) tmp[s] = T[(lg * 8 + s) * 80 + d];
    *reinterpret_cast<uint4*>(&Vt[(size_t)bh * 131072 + (size_t)d * 2048 + l0 + lg * 8]) =
      *reinterpret_cast<uint4*>(tmp);
  }
}

// ---------------- flash attention (S-transposed, packed P, max-free softmax) ----
// grid (32 q-tiles of 64, 32 bh) = 1024 blocks, 4 waves, each wave 16 q-rows,
// K-tile 64. S^T = mfma(kf, qf) puts 4 consecutive keys per lane -> P written
// as swizzled ds_write_b64; psum is one scalar per lane (q = lane&15).
__global__ __launch_bounds__(256) void attn_kernel(
    const u16* __restrict__ Qp, const u16* __restrict__ Kp,
    const u16* __restrict__ Vt, const int* __restrict__ mask,
    u16* __restrict__ ctx)
{
  __shared__ __align__(16) u16 Ks[64 * 64];     // [key][d chunks, xor-swizzled]  8 KB
  __shared__ __align__(16) u16 Vts[64 * 64];    // [d][key chunks, xor-swizzled]  8 KB
  __shared__ __align__(16) u16 Ps[4 * 16 * 64]; // per-wave [q][key b64 slots ^ q] 8 KB
  __shared__ __align__(16) float mb[64];

  const int tid = threadIdx.x;
  const int w = tid >> 6, ln = tid & 63;
  const int lm = ln & 15, lq = ln >> 4;
  const int bh = blockIdx.y, b = bh >> 4, h = bh & 15;
  const int q0 = blockIdx.x * 64;

  const u16* Qh = Qp + (size_t)b * 2048 * 1024 + h * 64;
  const u16* Kh = Kp + (size_t)b * 2048 * 1024 + h * 64;
  const u16* Vth = Vt + (size_t)bh * 64 * 2048;

  // persistent Q fragments (operand layout: idx=lane&15 -> q-row, k=lq*8+j -> d)
  const int qrow = q0 + w * 16 + lm;
  bf16x8 qf[2];
#pragma unroll
  for (int h2 = 0; h2 < 2; ++h2)
    qf[h2] = *reinterpret_cast<const bf16x8*>(Qh + (size_t)qrow * 1024 + h2 * 32 + lq * 8);

  const floatx4 z4 = {0.f, 0.f, 0.f, 0.f};
  floatx4 O[4];
#pragma unroll
  for (int j = 0; j < 4; ++j) O[j] = z4;
  float psum = 0.f;   // row-sum partial for q = lm (this lane's lq covers a key subset)

  u16* Pw = &Ps[w * 1024];
  const float SCL = 0.18033688011112042f;  // log2(e) / sqrt(64)

  for (int k0 = 0; k0 < 2048; k0 += 64) {
    // stage K [64 keys][64 d] and Vt [64 d][64 keys], chunk-swizzled (kc = s ^ row&7)
#pragma unroll
    for (int t = 0; t < 2; ++t) {
      int ci = t * 256 + tid;
      int row = ci >> 3, s = ci & 7;
      int kc = s ^ (row & 7);
      load_lds16(Kh + (size_t)(k0 + row) * 1024 + kc * 8, &Ks[(t * 256 + w * 64) * 8]);
      load_lds16(Vth + (size_t)row * 2048 + k0 + kc * 8, &Vts[(t * 256 + w * 64) * 8]);
    }
    if (tid < 64) mb[tid] = (mask[b * 2048 + k0 + tid] != 0) ? 0.f : -1e30f;
    __syncthreads();

    // fragment loads
    bf16x8 kf[4][2], vf[4][2];
#pragma unroll
    for (int n = 0; n < 4; ++n) {
      int key = n * 16 + lm;
#pragma unroll
      for (int h2 = 0; h2 < 2; ++h2) {
        int slot = (h2 * 4 + lq) ^ (key & 7);
        kf[n][h2] = *reinterpret_cast<const bf16x8*>(&Ks[key * 64 + slot * 8]);
      }
    }
#pragma unroll
    for (int j = 0; j < 4; ++j) {
      int d = j * 16 + lm;
#pragma unroll
      for (int h2 = 0; h2 < 2; ++h2) {
        int slot = (h2 * 4 + lq) ^ (d & 7);
        vf[j][h2] = *reinterpret_cast<const bf16x8*>(&Vts[d * 64 + slot * 8]);
      }
    }

    // S^T: D[key = lq*4+r (local, n-tile)][q = lm]
    floatx4 S[4];
#pragma unroll
    for (int n = 0; n < 4; ++n) {
      S[n] = __builtin_amdgcn_mfma_f32_16x16x32_bf16(kf[n][0], qf[0], z4, 0, 0, 0);
      S[n] = __builtin_amdgcn_mfma_f32_16x16x32_bf16(kf[n][1], qf[1], S[n], 0, 0, 0);
    }

    // p = exp2(S*SCL + maskbias); pack 4 keys -> one b64 write per n-tile
#pragma unroll
    for (int n = 0; n < 4; ++n) {
      float4 mbf = *reinterpret_cast<const float4*>(&mb[n * 16 + lq * 4]);
      float p0 = exp2f(S[n][0] * SCL + mbf.x);
      float p1 = exp2f(S[n][1] * SCL + mbf.y);
      float p2 = exp2f(S[n][2] * SCL + mbf.z);
      float p3 = exp2f(S[n][3] * SCL + mbf.w);
      psum += (p0 + p1) + (p2 + p3);
      uint2 pkd = make_uint2(pk2(p0, p1), pk2(p2, p3));
      int sp = (4 * n + lq) ^ lm;      // b64 slot swizzle by q-row
      *reinterpret_cast<uint2*>(&Pw[lm * 64 + sp * 4]) = pkd;
    }

    // O += P(16x64) * V(64x64); per-wave Ps, same-wave DS order -> no barrier
#pragma unroll
    for (int h2 = 0; h2 < 2; ++h2) {
      int s0 = 8 * h2 + 2 * lq;
      bf16x4 pa = *reinterpret_cast<const bf16x4*>(&Pw[lm * 64 + (s0 ^ lm) * 4]);
      bf16x4 pb = *reinterpret_cast<const bf16x4*>(&Pw[lm * 64 + ((s0 + 1) ^ lm) * 4]);
      bf16x8 pf = __builtin_shufflevector(pa, pb, 0, 1, 2, 3, 4, 5, 6, 7);
#pragma unroll
      for (int j = 0; j < 4; ++j)
        O[j] = __builtin_amdgcn_mfma_f32_16x16x32_bf16(pf, vf[j][h2], O[j], 0, 0, 0);
    }
    __syncthreads();
  }

  // epilogue: reduce psum across lq groups; normalize O (D[q=lq*4+r][d=lm])
  float s = psum;
  s += __shfl_xor(s, 16, 64);
  s += __shfl_xor(s, 32, 64);
#pragma unroll
  for (int r = 0; r < 4; ++r) {
    int srcl = (ln & 48) | (lq * 4 + r);
    float inv = 1.0f / __shfl(s, srcl, 64);
    int row = q0 + w * 16 + lq * 4 + r;
    size_t base = ((size_t)b * 2048 + row) * 1024 + h * 64 + lm;
#pragma unroll
    for (int j = 0; j < 4; ++j)
      ctx[base + j * 16] = f2bf(O[j][r] * inv);
  }
}

// ---------------- host ----------------
extern "C" void kernel_launch(void* const* d_in, const int* in_sizes, int n_in,
                              void* d_out, int out_size, void* d_ws, size_t ws_size,
                              hipStream_t stream) {
  const float* q  = (const float*)d_in[0];
  const float* k  = (const float*)d_in[1];
  const float* v  = (const float*)d_in[2];
  const int*   mk = (const int*)  d_in[3];
  const float* wq = (const float*)d_in[4];
  const float* wk = (const float*)d_in[5];
  const float* wv = (const float*)d_in[6];
  const float* wo = (const float*)d_in[7];
  const float* bo = (const float*)d_in[8];

  u16* ws16 = (u16*)d_ws;
  // element offsets (bf16): Xq=0 Xk=4M Xv=8M | Wq=12M Wk=13M Wv=14M Wo=15M
  // Qp=16M Kp=20M Vp=24M | Vt aliases Xq (dead), ctx aliases Xk.
  u16* Xq  = ws16;
  u16* Wq  = ws16 + 12 * MEG;
  u16* Wo  = ws16 + 15 * MEG;
  u16* Qp  = ws16 + 16 * MEG;
  u16* Kp  = ws16 + 20 * MEG;
  u16* Vp  = ws16 + 24 * MEG;
  u16* Vt  = ws16;            // alias Xq
  u16* ctx = ws16 + 4 * MEG;  // alias Xk

  cvt7<<<dim3(16384), dim3(256), 0, stream>>>(q, k, v, wq, wk, wv, wo, ws16);

  gemm_bt<true, false><<<dim3(8, 32, 3), dim3(256), 0, stream>>>(
      Xq, Wq, nullptr, (void*)Qp, 4096, 1024, 1024,
      (long)(4 * MEG), (long)MEG, (long)(4 * MEG));

  transpose_v<<<dim3(32, 32), dim3(256), 0, stream>>>(Vp, Vt);

  attn_kernel<<<dim3(32, 32), dim3(256), 0, stream>>>(Qp, Kp, Vt, mk, ctx);

  gemm_bt<false, true><<<dim3(8, 32, 1), dim3(256), 0, stream>>>(
      ctx, Wo, bo, d_out, 4096, 1024, 1024, 0, 0, 0);
}

// Round 4
// 239.157 us; speedup vs baseline: 1.5706x; 1.0913x over previous
//
#include <hip/hip_runtime.h>

typedef unsigned short u16;
typedef __bf16 bf16x8 __attribute__((ext_vector_type(8)));
typedef __bf16 bf16x4 __attribute__((ext_vector_type(4)));
typedef float floatx4 __attribute__((ext_vector_type(4)));
typedef u16 u16x4 __attribute__((ext_vector_type(4)));

#define MEG ((size_t)(1u << 20))

__device__ __forceinline__ u16 f2bf(float f) {
  unsigned int u = __float_as_uint(f);
  u += 0x7fffu + ((u >> 16) & 1u);   // round-to-nearest-even
  return (u16)(u >> 16);
}

// async global->LDS, 16B per lane; LDS dest = wave-uniform base + lane*16
__device__ __forceinline__ void load_lds16(const u16* g, u16* l) {
  __builtin_amdgcn_global_load_lds((const __attribute__((address_space(1))) unsigned int*)g,
                                   (__attribute__((address_space(3))) unsigned int*)l,
                                   16, 0, 0);
}

// ---------------- fp32 -> bf16 conversion of the 7 fp32 inputs ----------------
// layout (elements): [q 4M][k 4M][v 4M][Wq 1M][Wk 1M][Wv 1M][Wo 1M] = 16M
__global__ __launch_bounds__(256) void cvt7(
    const float* __restrict__ s0, const float* __restrict__ s1,
    const float* __restrict__ s2, const float* __restrict__ s3,
    const float* __restrict__ s4, const float* __restrict__ s5,
    const float* __restrict__ s6, u16* __restrict__ dst)
{
  size_t e = ((size_t)blockIdx.x * 256 + threadIdx.x) * 4;
  unsigned m = (unsigned)(e >> 20);
  const float* s; size_t off;
  if (m < 4)       { s = s0; off = e; }
  else if (m < 8)  { s = s1; off = e - 4 * MEG; }
  else if (m < 12) { s = s2; off = e - 8 * MEG; }
  else if (m < 13) { s = s3; off = e - 12 * MEG; }
  else if (m < 14) { s = s4; off = e - 13 * MEG; }
  else if (m < 15) { s = s5; off = e - 14 * MEG; }
  else             { s = s6; off = e - 15 * MEG; }
  float4 f = *reinterpret_cast<const float4*>(s + off);
  u16x4 o;
  o.x = f2bf(f.x); o.y = f2bf(f.y); o.z = f2bf(f.z); o.w = f2bf(f.w);
  *reinterpret_cast<u16x4*>(dst + e) = o;
}

// ---------------- generic C = A * B^T (+bias) bf16 MFMA GEMM, BK=64 ----------
// A: MxK bf16 row-major, B: NxK bf16 row-major, C: MxN (bf16 or fp32)
// 128x128 tile, BK=64, 256 threads = 4 waves (2x2), xor-chunk-swizzled LDS.
template<bool OUT_BF16, bool ADD_BIAS>
__global__ __launch_bounds__(256) void gemm_bt(
    const u16* __restrict__ Abase, const u16* __restrict__ Bbase,
    const float* __restrict__ bias, void* __restrict__ Cbase,
    int M, int N, int K, long zA, long zB, long zC)
{
  __shared__ __align__(16) u16 As[128 * 64];   // 16 KB, slot = c ^ (row&7)
  __shared__ __align__(16) u16 Bs[128 * 64];   // 16 KB
  const int tid = threadIdx.x;
  const int w = tid >> 6, ln = tid & 63;
  const int lm = ln & 15, lq = ln >> 4;
  const int wm = w >> 1, wn = w & 1;
  const long m0 = (long)blockIdx.y * 128, n0 = (long)blockIdx.x * 128;
  const u16* A = Abase + (size_t)blockIdx.z * (size_t)zA;
  const u16* B = Bbase + (size_t)blockIdx.z * (size_t)zB;

  // staging source pointers (row r0 = tid>>3, chunk kc = (tid&7)^(r0&7))
  const int r0 = tid >> 3;
  const int kc = (tid & 7) ^ (r0 & 7);
  const u16* gA = A + (m0 + r0) * (long)K + kc * 8;
  const u16* gB = B + (n0 + r0) * (long)K + kc * 8;
  const long rstep = 32L * K;

  // loop-invariant fragment base pointers
  const int sl0 = (lq ^ (lm & 7)) * 8;
  const int sl1 = ((4 + lq) ^ (lm & 7)) * 8;
  const u16* ab0 = &As[(wm * 64 + lm) * 64 + sl0];
  const u16* ab1 = &As[(wm * 64 + lm) * 64 + sl1];
  const u16* bb0 = &Bs[(wn * 64 + lm) * 64 + sl0];
  const u16* bb1 = &Bs[(wn * 64 + lm) * 64 + sl1];

  const floatx4 z4 = {0.f, 0.f, 0.f, 0.f};
  floatx4 acc[4][4];
#pragma unroll
  for (int i = 0; i < 4; ++i)
#pragma unroll
    for (int j = 0; j < 4; ++j) acc[i][j] = z4;

  for (int k0 = 0; k0 < K; k0 += 64) {
#pragma unroll
    for (int t = 0; t < 4; ++t) {
      load_lds16(gA + t * rstep, &As[(t * 256 + w * 64) * 8]);
      load_lds16(gB + t * rstep, &Bs[(t * 256 + w * 64) * 8]);
    }
    gA += 64; gB += 64;
    __syncthreads();
    bf16x8 af[4][2], bfr[4][2];
#pragma unroll
    for (int i = 0; i < 4; ++i) {
      af[i][0] = *reinterpret_cast<const bf16x8*>(ab0 + i * 1024);
      af[i][1] = *reinterpret_cast<const bf16x8*>(ab1 + i * 1024);
    }
#pragma unroll
    for (int j = 0; j < 4; ++j) {
      bfr[j][0] = *reinterpret_cast<const bf16x8*>(bb0 + j * 1024);
      bfr[j][1] = *reinterpret_cast<const bf16x8*>(bb1 + j * 1024);
    }
#pragma unroll
    for (int i = 0; i < 4; ++i)
#pragma unroll
      for (int j = 0; j < 4; ++j) {
        acc[i][j] = __builtin_amdgcn_mfma_f32_16x16x32_bf16(af[i][0], bfr[j][0], acc[i][j], 0, 0, 0);
        acc[i][j] = __builtin_amdgcn_mfma_f32_16x16x32_bf16(af[i][1], bfr[j][1], acc[i][j], 0, 0, 0);
      }
    __syncthreads();
  }

#pragma unroll
  for (int i = 0; i < 4; ++i) {
    long row = m0 + wm * 64 + i * 16 + lq * 4;
#pragma unroll
    for (int j = 0; j < 4; ++j) {
      long col = n0 + wn * 64 + j * 16 + lm;
#pragma unroll
      for (int r = 0; r < 4; ++r) {
        float v = acc[i][j][r];
        if (ADD_BIAS) v += bias[col];
        size_t idx = (size_t)(row + r) * (size_t)N + (size_t)col;
        if (OUT_BF16) (((u16*)Cbase) + (size_t)blockIdx.z * (size_t)zC)[idx] = f2bf(v);
        else ((float*)Cbase)[idx] = v;
      }
    }
  }
}

// ---------------- V (b,l,h*64+d) -> Vt (bh, d, l), LDS-tiled ----------------
__global__ __launch_bounds__(256) void transpose_v(const u16* __restrict__ Vp, u16* __restrict__ Vt)
{
  __shared__ u16 T[64 * 80];   // pitch 80 el keeps 16B alignment
  const int tid = threadIdx.x;
  const int bh = blockIdx.y, b = bh >> 4, h = bh & 15;
  const int l0 = blockIdx.x * 64;
#pragma unroll
  for (int t = 0; t < 2; ++t) {
    int ci = t * 256 + tid;
    int l = ci >> 3, c = ci & 7;
    *reinterpret_cast<uint4*>(&T[l * 80 + c * 8]) =
      *reinterpret_cast<const uint4*>(&Vp[((size_t)(b * 2048 + l0 + l)) * 1024 + h * 64 + c * 8]);
  }
  __syncthreads();
#pragma unroll
  for (int t = 0; t < 2; ++t) {
    int ci = t * 256 + tid;
    int d = ci >> 3, lg = ci & 7;
    u16 tmp[8];
#pragma unroll
    for (int s = 0; s < 8; ++s) tmp[s] = T[(lg * 8 + s) * 80 + d];
    *reinterpret_cast<uint4*>(&Vt[(size_t)bh * 131072 + (size_t)d * 2048 + l0 + lg * 8]) =
      *reinterpret_cast<uint4*>(tmp);
  }
}

// ---------------- flash attention (S-transposed, hoisted addrs, raw exp2) ----
// grid (32 q-tiles of 64, 32 bh) = 1024 blocks, 4 waves, 16 q-rows/wave, K-tile 64.
__global__ __launch_bounds__(256, 4) void attn_kernel(
    const u16* __restrict__ Qp, const u16* __restrict__ Kp,
    const u16* __restrict__ Vt, const int* __restrict__ mask,
    u16* __restrict__ ctx)
{
  __shared__ __align__(16) u16 Ks[64 * 64];      // 8 KB, slot = c ^ (key&7)
  __shared__ __align__(16) u16 Vts[64 * 64];     // 8 KB, slot = c ^ (d&7)
  __shared__ __align__(16) u16 Ps[4 * 16 * 64];  // 8 KB, per-wave
  __shared__ __align__(16) float mball[2048];    // 8 KB mask bias, staged once

  const int tid = threadIdx.x;
  const int w = tid >> 6, ln = tid & 63;
  const int lm = ln & 15, lq = ln >> 4;
  const int bh = blockIdx.y, b = bh >> 4, h = bh & 15;
  const int q0 = blockIdx.x * 64;

  const u16* Qh = Qp + (size_t)b * 2048 * 1024 + h * 64;
  const u16* Kh = Kp + (size_t)b * 2048 * 1024 + h * 64;
  const u16* Vth = Vt + (size_t)bh * 64 * 2048;

  // mask bias staged once (first __syncthreads covers visibility)
  const int* mrow = mask + b * 2048;
#pragma unroll
  for (int t = 0; t < 8; ++t) {
    int i = t * 256 + tid;
    mball[i] = (mrow[i] != 0) ? 0.f : -1e30f;
  }

  // persistent Q fragments (B-operand for S^T: n=lm -> q-row, k=lq*8+j -> d)
  const int qrow = q0 + w * 16 + lm;
  bf16x8 qf0 = *reinterpret_cast<const bf16x8*>(Qh + (size_t)qrow * 1024 + lq * 8);
  bf16x8 qf1 = *reinterpret_cast<const bf16x8*>(Qh + (size_t)qrow * 1024 + 32 + lq * 8);

  // loop-invariant LDS pointers
  const int sl0 = (lq ^ (lm & 7)) * 8;
  const int sl1 = ((4 + lq) ^ (lm & 7)) * 8;
  const u16* kb0 = &Ks[lm * 64 + sl0];
  const u16* kb1 = &Ks[lm * 64 + sl1];
  const u16* vb0 = &Vts[lm * 64 + sl0];
  const u16* vb1 = &Vts[lm * 64 + sl1];
  u16* Pw = &Ps[w * 1024];
  u16* pwr[4];
#pragma unroll
  for (int n = 0; n < 4; ++n) pwr[n] = &Pw[lm * 64 + (((4 * n + lq) ^ lm) * 4)];
  const u16* prd[4];
#pragma unroll
  for (int t = 0; t < 4; ++t)
    prd[t] = &Pw[lm * 64 + (((8 * (t >> 1) + 2 * lq + (t & 1)) ^ lm) * 4)];
  const float* mbi = mball + lq * 4;

  // staging source running pointers (row r0 = tid>>3, chunk kc = (tid&7)^(r0&7))
  const int r0 = tid >> 3;
  const int kc = (tid & 7) ^ (r0 & 7);
  const u16* gK0 = Kh + (size_t)r0 * 1024 + kc * 8;
  const u16* gK1 = gK0 + 32 * 1024;
  const u16* gV0 = Vth + (size_t)r0 * 2048 + kc * 8;
  const u16* gV1 = gV0 + 32 * 2048;

  const floatx4 z4 = {0.f, 0.f, 0.f, 0.f};
  floatx4 O[4];
#pragma unroll
  for (int j = 0; j < 4; ++j) O[j] = z4;
  float psum = 0.f;
  const float SCL = 0.18033688011112042f;  // log2(e) / sqrt(64)

  for (int it = 0; it < 32; ++it) {
    load_lds16(gK0, &Ks[(w * 64) * 8]);
    load_lds16(gK1, &Ks[(256 + w * 64) * 8]);
    load_lds16(gV0, &Vts[(w * 64) * 8]);
    load_lds16(gV1, &Vts[(256 + w * 64) * 8]);
    gK0 += 64 * 1024; gK1 += 64 * 1024; gV0 += 64; gV1 += 64;
    __syncthreads();

    // S^T = K_tile * Q^T : D[key_local = lq*4+r][q = lm]
    bf16x8 kf[4][2];
#pragma unroll
    for (int n = 0; n < 4; ++n) {
      kf[n][0] = *reinterpret_cast<const bf16x8*>(kb0 + n * 1024);
      kf[n][1] = *reinterpret_cast<const bf16x8*>(kb1 + n * 1024);
    }
    floatx4 S[4];
#pragma unroll
    for (int n = 0; n < 4; ++n) {
      S[n] = __builtin_amdgcn_mfma_f32_16x16x32_bf16(kf[n][0], qf0, z4, 0, 0, 0);
      S[n] = __builtin_amdgcn_mfma_f32_16x16x32_bf16(kf[n][1], qf1, S[n], 0, 0, 0);
    }

    // p = exp2(S*SCL + maskbias); raw v_exp; pack via +0x8000 + v_perm
#pragma unroll
    for (int n = 0; n < 4; ++n) {
      float4 m4 = *reinterpret_cast<const float4*>(mbi + n * 16);
      float p0 = __builtin_amdgcn_exp2f(fmaf(S[n][0], SCL, m4.x));
      float p1 = __builtin_amdgcn_exp2f(fmaf(S[n][1], SCL, m4.y));
      float p2 = __builtin_amdgcn_exp2f(fmaf(S[n][2], SCL, m4.z));
      float p3 = __builtin_amdgcn_exp2f(fmaf(S[n][3], SCL, m4.w));
      psum += (p0 + p1) + (p2 + p3);
      unsigned u0 = __float_as_uint(p0) + 0x8000u;
      unsigned u1 = __float_as_uint(p1) + 0x8000u;
      unsigned u2 = __float_as_uint(p2) + 0x8000u;
      unsigned u3 = __float_as_uint(p3) + 0x8000u;
      uint2 pk;
      pk.x = __builtin_amdgcn_perm(u1, u0, 0x07060302u);
      pk.y = __builtin_amdgcn_perm(u3, u2, 0x07060302u);
      *reinterpret_cast<uint2*>(pwr[n]) = pk;
    }

    // O += P(16x64) * V(64x64); per-wave Ps, same-wave DS order -> no barrier
#pragma unroll
    for (int h2 = 0; h2 < 2; ++h2) {
      bf16x4 pa = *reinterpret_cast<const bf16x4*>(prd[2 * h2]);
      bf16x4 pb = *reinterpret_cast<const bf16x4*>(prd[2 * h2 + 1]);
      bf16x8 pf = __builtin_shufflevector(pa, pb, 0, 1, 2, 3, 4, 5, 6, 7);
      const u16* vb = (h2 == 0) ? vb0 : vb1;
#pragma unroll
      for (int j = 0; j < 4; ++j) {
        bf16x8 vf = *reinterpret_cast<const bf16x8*>(vb + j * 1024);
        O[j] = __builtin_amdgcn_mfma_f32_16x16x32_bf16(pf, vf, O[j], 0, 0, 0);
      }
    }
    mbi += 64;
    __syncthreads();
  }

  // epilogue: reduce psum across lq groups; normalize O (D[q=lq*4+r][d=lm])
  float s = psum;
  s += __shfl_xor(s, 16, 64);
  s += __shfl_xor(s, 32, 64);
#pragma unroll
  for (int r = 0; r < 4; ++r) {
    int srcl = (ln & 48) | (lq * 4 + r);
    float inv = 1.0f / __shfl(s, srcl, 64);
    int row = q0 + w * 16 + lq * 4 + r;
    size_t base = ((size_t)b * 2048 + row) * 1024 + h * 64 + lm;
#pragma unroll
    for (int j = 0; j < 4; ++j)
      ctx[base + j * 16] = f2bf(O[j][r] * inv);
  }
}

// ---------------- host ----------------
extern "C" void kernel_launch(void* const* d_in, const int* in_sizes, int n_in,
                              void* d_out, int out_size, void* d_ws, size_t ws_size,
                              hipStream_t stream) {
  const float* q  = (const float*)d_in[0];
  const float* k  = (const float*)d_in[1];
  const float* v  = (const float*)d_in[2];
  const int*   mk = (const int*)  d_in[3];
  const float* wq = (const float*)d_in[4];
  const float* wk = (const float*)d_in[5];
  const float* wv = (const float*)d_in[6];
  const float* wo = (const float*)d_in[7];
  const float* bo = (const float*)d_in[8];

  u16* ws16 = (u16*)d_ws;
  // element offsets (bf16): Xq=0 Xk=4M Xv=8M | Wq=12M Wk=13M Wv=14M Wo=15M
  // Qp=16M Kp=20M Vp=24M | Vt aliases Xq (dead), ctx aliases Xk.
  u16* Xq  = ws16;
  u16* Wq  = ws16 + 12 * MEG;
  u16* Wo  = ws16 + 15 * MEG;
  u16* Qp  = ws16 + 16 * MEG;
  u16* Kp  = ws16 + 20 * MEG;
  u16* Vp  = ws16 + 24 * MEG;
  u16* Vt  = ws16;            // alias Xq
  u16* ctx = ws16 + 4 * MEG;  // alias Xk

  cvt7<<<dim3(16384), dim3(256), 0, stream>>>(q, k, v, wq, wk, wv, wo, ws16);

  gemm_bt<true, false><<<dim3(8, 32, 3), dim3(256), 0, stream>>>(
      Xq, Wq, nullptr, (void*)Qp, 4096, 1024, 1024,
      (long)(4 * MEG), (long)MEG, (long)(4 * MEG));

  transpose_v<<<dim3(32, 32), dim3(256), 0, stream>>>(Vp, Vt);

  attn_kernel<<<dim3(32, 32), dim3(256), 0, stream>>>(Qp, Kp, Vt, mk, ctx);

  gemm_bt<false, true><<<dim3(8, 32, 1), dim3(256), 0, stream>>>(
      ctx, Wo, bo, d_out, 4096, 1024, 1024, 0, 0, 0);
}

// Round 5
// 227.194 us; speedup vs baseline: 1.6533x; 1.0527x over previous
//
#include <hip/hip_runtime.h>

typedef unsigned short u16;
typedef __bf16 bf16x8 __attribute__((ext_vector_type(8)));
typedef __bf16 bf16x4 __attribute__((ext_vector_type(4)));
typedef float floatx4 __attribute__((ext_vector_type(4)));
typedef u16 u16x4 __attribute__((ext_vector_type(4)));

#define MEG ((size_t)(1u << 20))

__device__ __forceinline__ u16 f2bf(float f) {
  unsigned int u = __float_as_uint(f);
  u += 0x7fffu + ((u >> 16) & 1u);   // round-to-nearest-even
  return (u16)(u >> 16);
}

// async global->LDS, 16B per lane; LDS dest = wave-uniform base + lane*16
__device__ __forceinline__ void load_lds16(const u16* g, u16* l) {
  __builtin_amdgcn_global_load_lds((const __attribute__((address_space(1))) unsigned int*)g,
                                   (__attribute__((address_space(3))) unsigned int*)l,
                                   16, 0, 0);
}

// ---------------- fp32 -> bf16 conversion of the 7 fp32 inputs ----------------
// layout (elements): [q 4M][k 4M][v 4M][Wq 1M][Wk 1M][Wv 1M][Wo 1M] = 16M
__global__ __launch_bounds__(256) void cvt7(
    const float* __restrict__ s0, const float* __restrict__ s1,
    const float* __restrict__ s2, const float* __restrict__ s3,
    const float* __restrict__ s4, const float* __restrict__ s5,
    const float* __restrict__ s6, u16* __restrict__ dst)
{
  size_t e = ((size_t)blockIdx.x * 256 + threadIdx.x) * 4;
  unsigned m = (unsigned)(e >> 20);
  const float* s; size_t off;
  if (m < 4)       { s = s0; off = e; }
  else if (m < 8)  { s = s1; off = e - 4 * MEG; }
  else if (m < 12) { s = s2; off = e - 8 * MEG; }
  else if (m < 13) { s = s3; off = e - 12 * MEG; }
  else if (m < 14) { s = s4; off = e - 13 * MEG; }
  else if (m < 15) { s = s5; off = e - 14 * MEG; }
  else             { s = s6; off = e - 15 * MEG; }
  float4 f = *reinterpret_cast<const float4*>(s + off);
  u16x4 o;
  o.x = f2bf(f.x); o.y = f2bf(f.y); o.z = f2bf(f.z); o.w = f2bf(f.w);
  *reinterpret_cast<u16x4*>(dst + e) = o;
}

// ---------------- generic C = A * B^T (+bias) bf16 MFMA GEMM, BK=64 ----------
// A: MxK bf16 row-major, B: NxK bf16 row-major, C: MxN (bf16 or fp32)
// Tile (IT*32) x 128, 256 threads = 4 waves (2x2); IT=4 -> 128x128, IT=2 -> 64x128.
// xor-chunk-swizzled LDS (slot = c ^ (row&7)), conflict-free b128 frag reads.
template<int IT, bool OUT_BF16, bool ADD_BIAS>
__global__ __launch_bounds__(256) void gemm_bt(
    const u16* __restrict__ Abase, const u16* __restrict__ Bbase,
    const float* __restrict__ bias, void* __restrict__ Cbase,
    int M, int N, int K, long zA, long zB, long zC)
{
  __shared__ __align__(16) u16 As[IT * 32 * 64];
  __shared__ __align__(16) u16 Bs[128 * 64];
  const int tid = threadIdx.x;
  const int w = tid >> 6, ln = tid & 63;
  const int lm = ln & 15, lq = ln >> 4;
  const int wm = w >> 1, wn = w & 1;
  const long m0 = (long)blockIdx.y * (IT * 32), n0 = (long)blockIdx.x * 128;
  const u16* A = Abase + (size_t)blockIdx.z * (size_t)zA;
  const u16* B = Bbase + (size_t)blockIdx.z * (size_t)zB;

  // staging source pointers (row r0 = tid>>3, chunk kc = (tid&7)^(r0&7))
  const int r0 = tid >> 3;
  const int kc = (tid & 7) ^ (r0 & 7);
  const u16* gA = A + (m0 + r0) * (long)K + kc * 8;
  const u16* gB = B + (n0 + r0) * (long)K + kc * 8;
  const long rstep = 32L * K;

  // loop-invariant fragment base pointers
  const int sl0 = (lq ^ (lm & 7)) * 8;
  const int sl1 = ((4 + lq) ^ (lm & 7)) * 8;
  const u16* ab0 = &As[(wm * (IT * 16) + lm) * 64 + sl0];
  const u16* ab1 = &As[(wm * (IT * 16) + lm) * 64 + sl1];
  const u16* bb0 = &Bs[(wn * 64 + lm) * 64 + sl0];
  const u16* bb1 = &Bs[(wn * 64 + lm) * 64 + sl1];

  const floatx4 z4 = {0.f, 0.f, 0.f, 0.f};
  floatx4 acc[IT][4];
#pragma unroll
  for (int i = 0; i < IT; ++i)
#pragma unroll
    for (int j = 0; j < 4; ++j) acc[i][j] = z4;

  for (int k0 = 0; k0 < K; k0 += 64) {
#pragma unroll
    for (int t = 0; t < IT; ++t)
      load_lds16(gA + t * rstep, &As[(t * 256 + w * 64) * 8]);
#pragma unroll
    for (int t = 0; t < 4; ++t)
      load_lds16(gB + t * rstep, &Bs[(t * 256 + w * 64) * 8]);
    gA += 64; gB += 64;
    __syncthreads();
    bf16x8 af[IT][2], bfr[4][2];
#pragma unroll
    for (int i = 0; i < IT; ++i) {
      af[i][0] = *reinterpret_cast<const bf16x8*>(ab0 + i * 1024);
      af[i][1] = *reinterpret_cast<const bf16x8*>(ab1 + i * 1024);
    }
#pragma unroll
    for (int j = 0; j < 4; ++j) {
      bfr[j][0] = *reinterpret_cast<const bf16x8*>(bb0 + j * 1024);
      bfr[j][1] = *reinterpret_cast<const bf16x8*>(bb1 + j * 1024);
    }
#pragma unroll
    for (int i = 0; i < IT; ++i)
#pragma unroll
      for (int j = 0; j < 4; ++j) {
        acc[i][j] = __builtin_amdgcn_mfma_f32_16x16x32_bf16(af[i][0], bfr[j][0], acc[i][j], 0, 0, 0);
        acc[i][j] = __builtin_amdgcn_mfma_f32_16x16x32_bf16(af[i][1], bfr[j][1], acc[i][j], 0, 0, 0);
      }
    __syncthreads();
  }

#pragma unroll
  for (int i = 0; i < IT; ++i) {
    long row = m0 + wm * (IT * 16) + i * 16 + lq * 4;
#pragma unroll
    for (int j = 0; j < 4; ++j) {
      long col = n0 + wn * 64 + j * 16 + lm;
#pragma unroll
      for (int r = 0; r < 4; ++r) {
        float v = acc[i][j][r];
        if (ADD_BIAS) v += bias[col];
        size_t idx = (size_t)(row + r) * (size_t)N + (size_t)col;
        if (OUT_BF16) (((u16*)Cbase) + (size_t)blockIdx.z * (size_t)zC)[idx] = f2bf(v);
        else ((float*)Cbase)[idx] = v;
      }
    }
  }
}

// ---------------- V (b,l,h*64+d) -> Vt (bh, d, l), LDS-tiled ----------------
__global__ __launch_bounds__(256) void transpose_v(const u16* __restrict__ Vp, u16* __restrict__ Vt)
{
  __shared__ u16 T[64 * 80];   // pitch 80 el keeps 16B alignment
  const int tid = threadIdx.x;
  const int bh = blockIdx.y, b = bh >> 4, h = bh & 15;
  const int l0 = blockIdx.x * 64;
#pragma unroll
  for (int t = 0; t < 2; ++t) {
    int ci = t * 256 + tid;
    int l = ci >> 3, c = ci & 7;
    *reinterpret_cast<uint4*>(&T[l * 80 + c * 8]) =
      *reinterpret_cast<const uint4*>(&Vp[((size_t)(b * 2048 + l0 + l)) * 1024 + h * 64 + c * 8]);
  }
  __syncthreads();
#pragma unroll
  for (int t = 0; t < 2; ++t) {
    int ci = t * 256 + tid;
    int d = ci >> 3, lg = ci & 7;
    u16 tmp[8];
#pragma unroll
    for (int s = 0; s < 8; ++s) tmp[s] = T[(lg * 8 + s) * 80 + d];
    *reinterpret_cast<uint4*>(&Vt[(size_t)bh * 131072 + (size_t)d * 2048 + l0 + lg * 8]) =
      *reinterpret_cast<uint4*>(tmp);
  }
}

// ---------------- flash attention (S-transposed, 32 q/wave) ----------------
// grid (16 q-tiles of 128, 32 bh) = 512 blocks, 4 waves, 32 q-rows/wave
// (2 subtiles of 16), K-tile 64. K/V fragment reads amortized over 2x MFMA.
__global__ __launch_bounds__(256, 2) void attn_kernel(
    const u16* __restrict__ Qp, const u16* __restrict__ Kp,
    const u16* __restrict__ Vt, const int* __restrict__ mask,
    u16* __restrict__ ctx)
{
  __shared__ __align__(16) u16 Ks[64 * 64];       // 8 KB, slot = c ^ (key&7)
  __shared__ __align__(16) u16 Vts[64 * 64];      // 8 KB, slot = c ^ (d&7)
  __shared__ __align__(16) u16 Ps[4 * 32 * 64];   // 16 KB, per-wave, 2 subtiles
  __shared__ __align__(16) float mball[2048];     // 8 KB mask bias, staged once

  const int tid = threadIdx.x;
  const int w = tid >> 6, ln = tid & 63;
  const int lm = ln & 15, lq = ln >> 4;
  const int bh = blockIdx.y, b = bh >> 4, h = bh & 15;
  const int q0 = blockIdx.x * 128;

  const u16* Qh = Qp + (size_t)b * 2048 * 1024 + h * 64;
  const u16* Kh = Kp + (size_t)b * 2048 * 1024 + h * 64;
  const u16* Vth = Vt + (size_t)bh * 64 * 2048;

  // mask bias staged once (first __syncthreads covers visibility)
  const int* mrowp = mask + b * 2048;
#pragma unroll
  for (int t = 0; t < 8; ++t) {
    int i = t * 256 + tid;
    mball[i] = (mrowp[i] != 0) ? 0.f : -1e30f;
  }

  // persistent Q fragments (B-operand for S^T), 2 q-subtiles
  bf16x8 qf[2][2];
#pragma unroll
  for (int m = 0; m < 2; ++m) {
    int qrow = q0 + w * 32 + m * 16 + lm;
    qf[m][0] = *reinterpret_cast<const bf16x8*>(Qh + (size_t)qrow * 1024 + lq * 8);
    qf[m][1] = *reinterpret_cast<const bf16x8*>(Qh + (size_t)qrow * 1024 + 32 + lq * 8);
  }

  // loop-invariant LDS pointers
  const int sl0 = (lq ^ (lm & 7)) * 8;
  const int sl1 = ((4 + lq) ^ (lm & 7)) * 8;
  const u16* kb0 = &Ks[lm * 64 + sl0];
  const u16* kb1 = &Ks[lm * 64 + sl1];
  const u16* vb0 = &Vts[lm * 64 + sl0];
  const u16* vb1 = &Vts[lm * 64 + sl1];
  u16* Pw = &Ps[w * 2048];
  u16* pwr[4];
#pragma unroll
  for (int n = 0; n < 4; ++n) pwr[n] = &Pw[lm * 64 + (((4 * n + lq) ^ lm) * 4)];
  const u16* prd[4];
#pragma unroll
  for (int t = 0; t < 4; ++t)
    prd[t] = &Pw[lm * 64 + (((8 * (t >> 1) + 2 * lq + (t & 1)) ^ lm) * 4)];
  const float* mbi = mball + lq * 4;

  // staging source running pointers (row r0 = tid>>3, chunk kc = (tid&7)^(r0&7))
  const int r0 = tid >> 3;
  const int kc = (tid & 7) ^ (r0 & 7);
  const u16* gK0 = Kh + (size_t)r0 * 1024 + kc * 8;
  const u16* gK1 = gK0 + 32 * 1024;
  const u16* gV0 = Vth + (size_t)r0 * 2048 + kc * 8;
  const u16* gV1 = gV0 + 32 * 2048;

  const floatx4 z4 = {0.f, 0.f, 0.f, 0.f};
  floatx4 O[2][4];
#pragma unroll
  for (int m = 0; m < 2; ++m)
#pragma unroll
    for (int j = 0; j < 4; ++j) O[m][j] = z4;
  float psum[2] = {0.f, 0.f};
  const float SCL = 0.18033688011112042f;  // log2(e) / sqrt(64)

  for (int it = 0; it < 32; ++it) {
    load_lds16(gK0, &Ks[(w * 64) * 8]);
    load_lds16(gK1, &Ks[(256 + w * 64) * 8]);
    load_lds16(gV0, &Vts[(w * 64) * 8]);
    load_lds16(gV1, &Vts[(256 + w * 64) * 8]);
    gK0 += 64 * 1024; gK1 += 64 * 1024; gV0 += 64; gV1 += 64;
    __syncthreads();

    // shared fragments for both q-subtiles
    bf16x8 kf[4][2], vf[4][2];
#pragma unroll
    for (int n = 0; n < 4; ++n) {
      kf[n][0] = *reinterpret_cast<const bf16x8*>(kb0 + n * 1024);
      kf[n][1] = *reinterpret_cast<const bf16x8*>(kb1 + n * 1024);
    }
#pragma unroll
    for (int j = 0; j < 4; ++j) {
      vf[j][0] = *reinterpret_cast<const bf16x8*>(vb0 + j * 1024);
      vf[j][1] = *reinterpret_cast<const bf16x8*>(vb1 + j * 1024);
    }

#pragma unroll
    for (int m = 0; m < 2; ++m) {
      // S^T = K_tile * Q^T : D[key_local = lq*4+r][q = lm]
      floatx4 S[4];
#pragma unroll
      for (int n = 0; n < 4; ++n) {
        S[n] = __builtin_amdgcn_mfma_f32_16x16x32_bf16(kf[n][0], qf[m][0], z4, 0, 0, 0);
        S[n] = __builtin_amdgcn_mfma_f32_16x16x32_bf16(kf[n][1], qf[m][1], S[n], 0, 0, 0);
      }

      // p = exp2(S*SCL + maskbias); raw v_exp; pack via +0x8000 + v_perm
#pragma unroll
      for (int n = 0; n < 4; ++n) {
        float4 m4 = *reinterpret_cast<const float4*>(mbi + n * 16);
        float p0 = __builtin_amdgcn_exp2f(fmaf(S[n][0], SCL, m4.x));
        float p1 = __builtin_amdgcn_exp2f(fmaf(S[n][1], SCL, m4.y));
        float p2 = __builtin_amdgcn_exp2f(fmaf(S[n][2], SCL, m4.z));
        float p3 = __builtin_amdgcn_exp2f(fmaf(S[n][3], SCL, m4.w));
        psum[m] += (p0 + p1) + (p2 + p3);
        unsigned u0 = __float_as_uint(p0) + 0x8000u;
        unsigned u1 = __float_as_uint(p1) + 0x8000u;
        unsigned u2 = __float_as_uint(p2) + 0x8000u;
        unsigned u3 = __float_as_uint(p3) + 0x8000u;
        uint2 pk;
        pk.x = __builtin_amdgcn_perm(u1, u0, 0x07060302u);
        pk.y = __builtin_amdgcn_perm(u3, u2, 0x07060302u);
        *reinterpret_cast<uint2*>(pwr[n] + m * 1024) = pk;
      }

      // O += P(16x64) * V(64x64); per-wave Ps, same-wave DS order -> no barrier
#pragma unroll
      for (int h2 = 0; h2 < 2; ++h2) {
        bf16x4 pa = *reinterpret_cast<const bf16x4*>(prd[2 * h2] + m * 1024);
        bf16x4 pb = *reinterpret_cast<const bf16x4*>(prd[2 * h2 + 1] + m * 1024);
        bf16x8 pf = __builtin_shufflevector(pa, pb, 0, 1, 2, 3, 4, 5, 6, 7);
#pragma unroll
        for (int j = 0; j < 4; ++j)
          O[m][j] = __builtin_amdgcn_mfma_f32_16x16x32_bf16(pf, vf[j][h2], O[m][j], 0, 0, 0);
      }
    }
    mbi += 64;
    __syncthreads();
  }

  // epilogue: reduce psum across lq groups; normalize O (D[q=lq*4+r][d=lm])
#pragma unroll
  for (int m = 0; m < 2; ++m) {
    float s = psum[m];
    s += __shfl_xor(s, 16, 64);
    s += __shfl_xor(s, 32, 64);
#pragma unroll
    for (int r = 0; r < 4; ++r) {
      int srcl = (ln & 48) | (lq * 4 + r);
      float inv = 1.0f / __shfl(s, srcl, 64);
      int row = q0 + w * 32 + m * 16 + lq * 4 + r;
      size_t base = ((size_t)b * 2048 + row) * 1024 + h * 64 + lm;
#pragma unroll
      for (int j = 0; j < 4; ++j)
        ctx[base + j * 16] = f2bf(O[m][j][r] * inv);
    }
  }
}

// ---------------- host ----------------
extern "C" void kernel_launch(void* const* d_in, const int* in_sizes, int n_in,
                              void* d_out, int out_size, void* d_ws, size_t ws_size,
                              hipStream_t stream) {
  const float* q  = (const float*)d_in[0];
  const float* k  = (const float*)d_in[1];
  const float* v  = (const float*)d_in[2];
  const int*   mk = (const int*)  d_in[3];
  const float* wq = (const float*)d_in[4];
  const float* wk = (const float*)d_in[5];
  const float* wv = (const float*)d_in[6];
  const float* wo = (const float*)d_in[7];
  const float* bo = (const float*)d_in[8];

  u16* ws16 = (u16*)d_ws;
  // element offsets (bf16): Xq=0 Xk=4M Xv=8M | Wq=12M Wk=13M Wv=14M Wo=15M
  // Qp=16M Kp=20M Vp=24M | Vt aliases Xq (dead), ctx aliases Xk.
  u16* Xq  = ws16;
  u16* Wq  = ws16 + 12 * MEG;
  u16* Wo  = ws16 + 15 * MEG;
  u16* Qp  = ws16 + 16 * MEG;
  u16* Kp  = ws16 + 20 * MEG;
  u16* Vp  = ws16 + 24 * MEG;
  u16* Vt  = ws16;            // alias Xq
  u16* ctx = ws16 + 4 * MEG;  // alias Xk

  cvt7<<<dim3(16384), dim3(256), 0, stream>>>(q, k, v, wq, wk, wv, wo, ws16);

  gemm_bt<4, true, false><<<dim3(8, 32, 3), dim3(256), 0, stream>>>(
      Xq, Wq, nullptr, (void*)Qp, 4096, 1024, 1024,
      (long)(4 * MEG), (long)MEG, (long)(4 * MEG));

  transpose_v<<<dim3(32, 32), dim3(256), 0, stream>>>(Vp, Vt);

  attn_kernel<<<dim3(16, 32), dim3(256), 0, stream>>>(Qp, Kp, Vt, mk, ctx);

  gemm_bt<2, false, true><<<dim3(8, 64, 1), dim3(256), 0, stream>>>(
      ctx, Wo, bo, d_out, 4096, 1024, 1024, 0, 0, 0);
}